// Round 4
// baseline (672.327 us; speedup 1.0000x reference)
//
#include <hip/hip_runtime.h>
#include <float.h>

#define F_DIM 256
#define N_DIM 512
#define B_DIM 192
#define K_TOP 10

typedef __attribute__((ext_vector_type(8))) short short8;
typedef __attribute__((ext_vector_type(4))) float f32x4;

__device__ inline unsigned short f2bf(float x) {
    unsigned u = __builtin_bit_cast(unsigned, x);
    return (unsigned short)((u + 0x7fffu + ((u >> 16) & 1u)) >> 16);
}

// ---------------------------------------------------------------------------
// k_combine (grid 514):
//   bx<256 : Wt1[j][f=bx] = bf16( sum_h g_w[h,f]*w1[h,j] )
//   bx==256: bc[j] = sum_h g_b[h]*w1[h,j]
//   bx>256 : W2t[j][f] = bf16(w2[f][j])
// ---------------------------------------------------------------------------
__global__ __launch_bounds__(256) void k_combine(const float* __restrict__ g_w,
                                                 const float* __restrict__ g_b,
                                                 const float* __restrict__ w1,
                                                 const float* __restrict__ w2,
                                                 unsigned short* __restrict__ Wt1,
                                                 float* __restrict__ bc,
                                                 unsigned short* __restrict__ W2t) {
    const int j = threadIdx.x;
    const int bx = blockIdx.x;
    if (bx < F_DIM) {
        float acc = 0.f;
        for (int h = 0; h < F_DIM; ++h) acc += g_w[h * F_DIM + bx] * w1[h * F_DIM + j];
        Wt1[j * F_DIM + bx] = f2bf(acc);
    } else if (bx == F_DIM) {
        float acc = 0.f;
        for (int h = 0; h < F_DIM; ++h) acc += g_b[h] * w1[h * F_DIM + j];
        bc[j] = acc;
    } else {
        int f = bx - F_DIM - 1;
        W2t[j * F_DIM + f] = f2bf(w2[f * F_DIM + j]);
    }
}

// ---------------------------------------------------------------------------
// k_to_bf16t: vt[b][n][f] = bf16(v[b][f][n])
// ---------------------------------------------------------------------------
__global__ __launch_bounds__(256) void k_to_bf16t(const float* __restrict__ v,
                                                  unsigned short* __restrict__ vt) {
    __shared__ float tile[32][33];
    const int b = blockIdx.z;
    const int n0 = blockIdx.x * 32;
    const int f0 = blockIdx.y * 32;
    const int tx = threadIdx.x & 31, ty = threadIdx.x >> 5;
    const float* vb = v + (size_t)b * F_DIM * N_DIM;
#pragma unroll
    for (int q = 0; q < 4; ++q)
        tile[ty + q * 8][tx] = vb[(size_t)(f0 + ty + q * 8) * N_DIM + n0 + tx];
    __syncthreads();
    const int wn = threadIdx.x >> 4;
    const int wf = threadIdx.x & 15;
    unsigned* vt32 = (unsigned*)vt;
#pragma unroll
    for (int q2 = 0; q2 < 2; ++q2) {
        int row = wn + q2 * 16;
        unsigned lo = f2bf(tile[wf * 2][row]);
        unsigned hi = f2bf(tile[wf * 2 + 1][row]);
        vt32[(size_t)(b * N_DIM + n0 + row) * (F_DIM / 2) + (f0 >> 1) + wf] = lo | (hi << 16);
    }
}

// ---------------------------------------------------------------------------
// k_topk_reg: block = 64 rows (4 waves x 16). Register-direct MFMA A = vt vt^T,
// in-register top-10. XCD-aware remap: all 8 blocks of a batch share one XCD's
// L2 (panel = 256 KB; ~8 concurrent batches/XCD = 2 MB < 4 MB L2).
// ---------------------------------------------------------------------------
__global__ __launch_bounds__(256, 2) void k_topk_reg(const unsigned short* __restrict__ vt,
                                                     float* __restrict__ deg,
                                                     int* __restrict__ idxb,
                                                     float* __restrict__ wb) {
    // remap: lid -> (batch, nblk) such that batch % 8 == XCD of this block
    const int lid = blockIdx.y * 8 + blockIdx.x;   // dispatch order, x-fastest
    const int slot = lid >> 3;                     // 0..191
    const int b = (lid & 7) + 8 * (slot >> 3);     // 24 batches per XCD
    const int nblk = slot & 7;

    const int w = threadIdx.x >> 6;
    const int l = threadIdx.x & 63;
    const int l15 = l & 15;
    const int g = l >> 4;
    const int n0w = nblk * 64 + w * 16;
    const unsigned short* vtb = vt + (size_t)b * N_DIM * F_DIM;

    short8 af[8];
#pragma unroll
    for (int s = 0; s < 8; ++s)
        af[s] = *(const short8*)(vtb + (size_t)(n0w + l15) * F_DIM + s * 32 + g * 8);

    f32x4 acc[32];
#pragma unroll
    for (int mt = 0; mt < 32; ++mt) acc[mt] = (f32x4){0.f, 0.f, 0.f, 0.f};

#pragma unroll
    for (int mt = 0; mt < 32; ++mt) {
        const unsigned short* bp = vtb + (size_t)(mt * 16 + l15) * F_DIM + g * 8;
#pragma unroll
        for (int s = 0; s < 8; ++s) {
            short8 bf = *(const short8*)(bp + s * 32);
            acc[mt] = __builtin_amdgcn_mfma_f32_16x16x32_bf16(af[s], bf, acc[mt], 0, 0, 0);
        }
    }

#pragma unroll
    for (int q = 0; q < 4; ++q) {
        float wv[32];
#pragma unroll
        for (int mt = 0; mt < 32; ++mt) wv[mt] = acc[mt][q];
        const int row = b * N_DIM + n0w + g * 4 + q;
        float sum = 0.f;
        for (int it = 0; it < K_TOP; ++it) {
            float bv = wv[0]; int bi = l15;
#pragma unroll
            for (int mt = 1; mt < 32; ++mt) {
                int ci = mt * 16 + l15;
                if (wv[mt] > bv) { bv = wv[mt]; bi = ci; }
            }
#pragma unroll
            for (int off = 1; off <= 8; off <<= 1) {
                float ov = __shfl_xor(bv, off, 64);
                int   oi = __shfl_xor(bi, off, 64);
                if (ov > bv || (ov == bv && oi < bi)) { bv = ov; bi = oi; }
            }
            sum += bv;
            if ((bi & 15) == l15) {
                int kmt = bi >> 4;
#pragma unroll
                for (int mt = 0; mt < 32; ++mt)
                    if (mt == kmt) wv[mt] = -FLT_MAX;
            }
            if (l15 == 0) {
                idxb[row * K_TOP + it] = bi;
                wb[row * (K_TOP + 1) + it] = bv;
            }
        }
        if (l15 == 0) deg[row] = sum + 1.0f;
    }
}

// ---------------------------------------------------------------------------
// k_gemm_mfma: per batch C[512,256] = At(bf16) @ Wt^T(bf16), register-direct
// ---------------------------------------------------------------------------
template <bool ADD_BIAS>
__global__ __launch_bounds__(256, 2) void k_gemm_mfma(const unsigned short* __restrict__ At,
                                                      const unsigned short* __restrict__ Wt,
                                                      const float* __restrict__ bias,
                                                      float* __restrict__ C) {
    const int b = blockIdx.y;
    const int w = threadIdx.x >> 6;
    const int l = threadIdx.x & 63;
    const int l15 = l & 15;
    const int g = l >> 4;
    const int n0w = blockIdx.x * 128 + w * 32;
    const unsigned short* Ab = At + (size_t)b * N_DIM * F_DIM;

    f32x4 acc0[16], acc1[16];
#pragma unroll
    for (int jt = 0; jt < 16; ++jt) {
        acc0[jt] = (f32x4){0.f, 0.f, 0.f, 0.f};
        acc1[jt] = (f32x4){0.f, 0.f, 0.f, 0.f};
    }

    for (int s = 0; s < 8; ++s) {
        short8 a0 = *(const short8*)(Ab + (size_t)(n0w + l15) * F_DIM + s * 32 + g * 8);
        short8 a1 = *(const short8*)(Ab + (size_t)(n0w + 16 + l15) * F_DIM + s * 32 + g * 8);
#pragma unroll
        for (int jt = 0; jt < 16; ++jt) {
            short8 bf = *(const short8*)(Wt + (size_t)(jt * 16 + l15) * F_DIM + s * 32 + g * 8);
            acc0[jt] = __builtin_amdgcn_mfma_f32_16x16x32_bf16(a0, bf, acc0[jt], 0, 0, 0);
            acc1[jt] = __builtin_amdgcn_mfma_f32_16x16x32_bf16(a1, bf, acc1[jt], 0, 0, 0);
        }
    }

#pragma unroll
    for (int jt = 0; jt < 16; ++jt) {
        float bv = ADD_BIAS ? bias[jt * 16 + l15] : 0.f;
#pragma unroll
        for (int q = 0; q < 4; ++q) {
            int r0 = n0w + g * 4 + q;
            C[((size_t)b * N_DIM + r0) * F_DIM + jt * 16 + l15] = acc0[jt][q] + bv;
            int r1 = n0w + 16 + g * 4 + q;
            C[((size_t)b * N_DIM + r1) * F_DIM + jt * 16 + l15] = acc1[jt][q] + bv;
        }
    }
}

// ---------------------------------------------------------------------------
// k_spmm_bf16: x1 = relu(A_hat @ h1 + b1), scale fused (recompute dn*a*dm from
// deg, identical op order to old k_scale). bf16 output. XCD remap.
// ---------------------------------------------------------------------------
__global__ __launch_bounds__(256) void k_spmm_bf16(const float* __restrict__ X,
                                                   const int* __restrict__ idxb,
                                                   const float* __restrict__ wbr,
                                                   const float* __restrict__ deg,
                                                   const float* __restrict__ bias,
                                                   unsigned short* __restrict__ Y) {
    const int lid = blockIdx.x;                 // 24576 blocks
    const int slot = lid >> 3;                  // 0..3071
    const int b = (lid & 7) + 8 * (slot >> 7);  // 24 batches per XCD
    const int rowblk = slot & 127;
    const int w = threadIdx.x >> 6;
    const int l = threadIdx.x & 63;
    const int row = b * N_DIM + rowblk * 4 + w;

    const float* Xb = X + ((size_t)b << 9) * F_DIM;
    const float* degb = deg + b * N_DIM;
    const int* id = idxb + row * K_TOP;
    const float* raw = wbr + row * (K_TOP + 1);

    const float dgs = deg[row];
    const float dn = (dgs == 0.f) ? 0.f : 1.f / sqrtf(dgs);
    float4 bv = ((const float4*)bias)[l];
    float4 xv = ((const float4*)(X + (size_t)row * F_DIM))[l];
    const float ws = dn * dn;
    float4 acc;
    acc.x = ws * xv.x + bv.x; acc.y = ws * xv.y + bv.y;
    acc.z = ws * xv.z + bv.z; acc.w = ws * xv.w + bv.w;
#pragma unroll
    for (int i = 0; i < K_TOP; ++i) {
        int m = id[i];
        float dgm = degb[m];
        float dm = (dgm == 0.f) ? 0.f : 1.f / sqrtf(dgm);
        float wi = dn * raw[i] * dm;
        float4 gv = ((const float4*)(Xb + ((size_t)m << 8)))[l];
        acc.x += wi * gv.x; acc.y += wi * gv.y;
        acc.z += wi * gv.z; acc.w += wi * gv.w;
    }
    acc.x = fmaxf(acc.x, 0.f); acc.y = fmaxf(acc.y, 0.f);
    acc.z = fmaxf(acc.z, 0.f); acc.w = fmaxf(acc.w, 0.f);
    uint2 p;
    p.x = (unsigned)f2bf(acc.x) | ((unsigned)f2bf(acc.y) << 16);
    p.y = (unsigned)f2bf(acc.z) | ((unsigned)f2bf(acc.w) << 16);
    ((uint2*)Y)[(size_t)row * (F_DIM / 4) + l] = p;
}

// ---------------------------------------------------------------------------
// k_spmm_trans: x2 = A_hat @ h2 + b2 (scale fused), then out[b,f,n] = x2 + v
// via LDS transpose. Block = 32 rows. XCD remap.
// ---------------------------------------------------------------------------
__global__ __launch_bounds__(256) void k_spmm_trans(const float* __restrict__ X,
                                                    const int* __restrict__ idxb,
                                                    const float* __restrict__ wbr,
                                                    const float* __restrict__ deg,
                                                    const float* __restrict__ bias,
                                                    const float* __restrict__ v,
                                                    float* __restrict__ out) {
    __shared__ float tile[32][257];
    const int lid = blockIdx.x;                 // 3072 blocks
    const int slot = lid >> 3;                  // 0..383
    const int b = (lid & 7) + 8 * (slot >> 4);
    const int n0 = (slot & 15) * 32;
    const int w = threadIdx.x >> 6;
    const int l = threadIdx.x & 63;

    const float* Xb = X + ((size_t)b << 9) * F_DIM;
    const float* degb = deg + b * N_DIM;
    float4 bv = ((const float4*)bias)[l];

    for (int r8 = 0; r8 < 8; ++r8) {
        const int rloc = w * 8 + r8;
        const int row = b * N_DIM + n0 + rloc;
        const int* id = idxb + row * K_TOP;
        const float* raw = wbr + row * (K_TOP + 1);
        const float dgs = deg[row];
        const float dn = (dgs == 0.f) ? 0.f : 1.f / sqrtf(dgs);
        float4 xv = ((const float4*)(X + (size_t)row * F_DIM))[l];
        const float ws = dn * dn;
        float4 acc;
        acc.x = ws * xv.x + bv.x; acc.y = ws * xv.y + bv.y;
        acc.z = ws * xv.z + bv.z; acc.w = ws * xv.w + bv.w;
#pragma unroll
        for (int i = 0; i < K_TOP; ++i) {
            int m = id[i];
            float dgm = degb[m];
            float dm = (dgm == 0.f) ? 0.f : 1.f / sqrtf(dgm);
            float wi = dn * raw[i] * dm;
            float4 gv = ((const float4*)(Xb + ((size_t)m << 8)))[l];
            acc.x += wi * gv.x; acc.y += wi * gv.y;
            acc.z += wi * gv.z; acc.w += wi * gv.w;
        }
        tile[rloc][l * 4 + 0] = acc.x;
        tile[rloc][l * 4 + 1] = acc.y;
        tile[rloc][l * 4 + 2] = acc.z;
        tile[rloc][l * 4 + 3] = acc.w;
    }
    __syncthreads();

    const int i8 = l & 7;    // n-quad index
    const int j8 = l >> 3;   // f offset within 8-f group
#pragma unroll
    for (int k = 0; k < 8; ++k) {
        const int f = (k * 4 + w) * 8 + j8;
        const size_t vo = (size_t)b * F_DIM * N_DIM + (size_t)f * N_DIM + n0;
        float4 vv = ((const float4*)(v + vo))[i8];
        float4 o;
        o.x = tile[i8 * 4 + 0][f] + vv.x;
        o.y = tile[i8 * 4 + 1][f] + vv.y;
        o.z = tile[i8 * 4 + 2][f] + vv.z;
        o.w = tile[i8 * 4 + 3][f] + vv.w;
        ((float4*)(out + vo))[i8] = o;
    }
}

// ---------------------------------------------------------------------------
extern "C" void kernel_launch(void* const* d_in, const int* in_sizes, int n_in,
                              void* d_out, int out_size, void* d_ws, size_t ws_size,
                              hipStream_t stream) {
    const float* v   = (const float*)d_in[0];
    const float* g_w = (const float*)d_in[1];
    const float* g_b = (const float*)d_in[2];
    const float* w1  = (const float*)d_in[3];
    const float* b1  = (const float*)d_in[4];
    const float* w2  = (const float*)d_in[5];
    const float* b2  = (const float*)d_in[6];
    float* out = (float*)d_out;

    const size_t S = (size_t)B_DIM * N_DIM * F_DIM;
    float* bufA = (float*)d_ws;                     // h1, then h2 (fp32)
    float* bufB = bufA + S;                         // vt(bf16) -> x1bf(bf16)
    float* bc   = bufB + S;
    float* deg  = bc + F_DIM;
    float* wb   = deg + (size_t)B_DIM * N_DIM;      // raw top-10 values
    int*   idxb = (int*)(wb + (size_t)B_DIM * N_DIM * (K_TOP + 1));
    unsigned short* Wt1 = (unsigned short*)(idxb + (size_t)B_DIM * N_DIM * K_TOP);
    unsigned short* W2t = Wt1 + F_DIM * F_DIM;

    unsigned short* vt   = (unsigned short*)bufB;
    unsigned short* x1bf = (unsigned short*)bufB;   // overwrites vt (dead after gemm1)

    k_combine<<<dim3(2 * F_DIM + 2), 256, 0, stream>>>(g_w, g_b, w1, w2, Wt1, bc, W2t);
    k_to_bf16t<<<dim3(N_DIM / 32, F_DIM / 32, B_DIM), 256, 0, stream>>>(v, vt);
    k_topk_reg<<<dim3(N_DIM / 64, B_DIM), 256, 0, stream>>>(vt, deg, idxb, wb);
    // h1 = vt @ Wt1^T + bc -> bufA
    k_gemm_mfma<true><<<dim3(N_DIM / 128, B_DIM), 256, 0, stream>>>(vt, Wt1, bc, bufA);
    // x1 = relu(A_hat @ h1 + b1) -> x1bf (bf16), scale fused
    k_spmm_bf16<<<dim3(B_DIM * N_DIM / 4), 256, 0, stream>>>(bufA, idxb, wb, deg, b1, x1bf);
    // h2 = x1bf @ W2t^T -> bufA
    k_gemm_mfma<false><<<dim3(N_DIM / 128, B_DIM), 256, 0, stream>>>(x1bf, W2t, nullptr, bufA);
    // out = (A_hat @ h2 + b2)^T + v, scale+transpose+residual fused
    k_spmm_trans<<<dim3(B_DIM * N_DIM / 32), 256, 0, stream>>>(bufA, idxb, wb, deg, b2, v, out);
}